// Round 9
// baseline (107.307 us; speedup 1.0000x reference)
//
#include <hip/hip_runtime.h>

// CIN, d-contraction-first, R9: split fused kernel into overlapping launches.
//   pack   : W0/W1 -> MFMA A-frag order (bf16) in ws          (unchanged)
//   phaseA : 512 blocks x 512 thr, G=4, 2 blocks/CU. phases 1+2a+2b of R8;
//            U written to global Ug[group][chunk][g(8)][k(32)] bf16 frag layout
//   phaseB : 512 blocks (group x k-half) x 512 thr, 2 blocks/CU. out2 partial
//            GEMM: A = wA2 frags (L2), B = Ug staged to LDS. -> P[kh] slabs
//   reduce : out2 = P[0] + P[1]
// Cross-kernel dependency via stream order (no atomics / coop launch).

#define F0   39
#define D_   16
#define H_   128
#define P0_  1521
#define P1_  4992
#define NF1  (F0 * 2 * 8)   // 624 layer-1 A-frags
#define NF2  (F0 * 4 * 8)   // 1248 W1 A-frags
#define NCH  156            // out2 k-chunks (4992/32)
#define SR4  72             // phaseA S_bf row stride in shorts (144B, 16B-aligned)
// R8 fused fallback constants
#define G8   8
#define SROW 136
#define UGS  136
#define UFS  1096

typedef __attribute__((ext_vector_type(8))) short   short8;
typedef __attribute__((ext_vector_type(8))) __bf16  bf16x8;
typedef __attribute__((ext_vector_type(4))) float   floatx4;

__device__ __forceinline__ unsigned short bf16rne(float f) {
  unsigned int u = __float_as_uint(f);
  u += 0x7FFFu + ((u >> 16) & 1u);
  return (unsigned short)(u >> 16);
}

__device__ __forceinline__ floatx4 mfma16(short8 a, short8 b, floatx4 c) {
  return __builtin_amdgcn_mfma_f32_16x16x32_bf16(
      __builtin_bit_cast(bf16x8, a), __builtin_bit_cast(bf16x8, b), c, 0, 0, 0);
}

// ---------- pack W into MFMA A-frag order (verified R3-R8) ----------
__global__ __launch_bounds__(256) void pack_w_kernel(const float* __restrict__ w0,
                                                     const float* __restrict__ w1,
                                                     short8* __restrict__ wA1,
                                                     short8* __restrict__ wA2) {
  int id = blockIdx.x * 256 + threadIdx.x;
  union { short8 v; unsigned short e[8]; } pk;
  if (id < NF1 * 64) {
    int lane = id & 63, frag = id >> 6;
    int t = frag & 7, s = (frag >> 3) & 1, f = frag >> 4;
    int m = t * 16 + (lane & 15);
    int qb = s * 32 + (lane >> 4) * 8;
#pragma unroll
    for (int j = 0; j < 8; ++j) {
      int q = qb + j;
      float v = (q < F0) ? w0[(size_t)m * P0_ + f * F0 + q] : 0.f;
      pk.e[j] = bf16rne(v);
    }
    wA1[frag * 64 + lane] = pk.v;
  } else if (id < (NF1 + NF2) * 64) {
    int u = id - NF1 * 64;
    int lane = u & 63, frag = u >> 6;
    int t = frag & 7, s = (frag >> 3) & 3, f = frag >> 5;
    int m = t * 16 + (lane & 15);
    int pb = f * 128 + s * 32 + (lane >> 4) * 8;
#pragma unroll
    for (int j = 0; j < 8; ++j) pk.e[j] = bf16rne(w1[(size_t)m * P1_ + pb + j]);
    wA2[frag * 64 + lane] = pk.v;
  }
}

// ---------- phase A: layer1 + out1 + U -> global frag slab ----------
__global__ __launch_bounds__(512, 4) void cin_phaseA(const float* __restrict__ x,
                                                     const short8* __restrict__ wA1,
                                                     float* __restrict__ out,
                                                     unsigned short* __restrict__ Ug) {
  __shared__ __align__(16) float xs[4][F0][D_];                 // 9984 B
  __shared__ __align__(16) unsigned short xTb[4 * 8 * D_ * 8];  // 8 KB
  __shared__ __align__(16) unsigned short S_bf[128 * SR4];      // 18.4 KB

  const int tid   = threadIdx.x;
  const int lane  = tid & 63;
  const int wv    = tid >> 6;      // 8 waves
  const int col   = lane & 15;
  const int quad  = lane >> 4;
  const int b0    = blockIdx.x * 4;
  const int group = blockIdx.x >> 1;
  const int ghalf = blockIdx.x & 1;
  const floatx4 zf4 = {0.f, 0.f, 0.f, 0.f};

  // ---- stage x (coalesced float4) ----
  {
    const float4* xg = (const float4*)(x + (size_t)b0 * (F0 * D_));
    float4* xl = (float4*)xs;
    for (int i = tid; i < 4 * F0 * D_ / 4; i += 512) xl[i] = xg[i];
  }
  __syncthreads();

  // ---- xTb[g][q8][d][j] = bf16(x[g][q8*8+j][d]), zero-pad q>=39 ----
  {
    int i = tid;  // exactly 512 entries
    int d = i & 15, q8 = (i >> 4) & 7, g = i >> 7;
    union { short8 v; unsigned short e[8]; } pk;
#pragma unroll
    for (int j = 0; j < 8; ++j) {
      int q = q8 * 8 + j;
      pk.e[j] = (q < F0) ? bf16rne(xs[g][q][d]) : (unsigned short)0;
    }
    *(short8*)&xTb[(size_t)i * 8] = pk.v;
  }
  __syncthreads();

  // ===== phase 1: wave = t; 4 local batches =====
  {
    const int t = wv;
    short8 bx[2][4];
#pragma unroll
    for (int s = 0; s < 2; ++s)
#pragma unroll
      for (int gi = 0; gi < 4; ++gi)
        bx[s][gi] = *(const short8*)&xTb[(size_t)(((gi * 8 + s * 4 + quad) * 16) + col) * 8];

    floatx4 acc2[4];
#pragma unroll
    for (int gi = 0; gi < 4; ++gi) acc2[gi] = zf4;

    short8 a0 = wA1[(size_t)(0 * 8 + t) * 64 + lane];
    short8 a1 = wA1[(size_t)(1 * 8 + t) * 64 + lane];
    for (int f = 0; f < F0; ++f) {
      int fn = (f + 1 < F0) ? f + 1 : f;
      short8 na0 = wA1[(size_t)((fn * 2 + 0) * 8 + t) * 64 + lane];
      short8 na1 = wA1[(size_t)((fn * 2 + 1) * 8 + t) * 64 + lane];
      float sx[4];
#pragma unroll
      for (int gi = 0; gi < 4; ++gi) sx[gi] = xs[gi][f][col];
#pragma unroll
      for (int gi = 0; gi < 4; ++gi) {
        floatx4 acf = mfma16(a0, bx[0][gi], zf4);
        acf = mfma16(a1, bx[1][gi], acf);
#pragma unroll
        for (int r = 0; r < 4; ++r) acc2[gi][r] += acf[r] * sx[gi];
      }
      a0 = na0; a1 = na1;
    }
#pragma unroll
    for (int gi = 0; gi < 4; ++gi)
#pragma unroll
      for (int r = 0; r < 4; ++r)
        S_bf[(size_t)((t * 16 + quad * 4 + r) * SR4) + gi * 16 + col] =
            bf16rne(acc2[gi][r]);
  }
  __syncthreads();

  // ===== phase 2a: out1[b,h] = sum_d h1 (512 threads, one shot) =====
  {
    int h = tid & 127, g = tid >> 7;
    union { short8 v; unsigned int u[4]; } w0v, w1v;
    w0v.v = *(const short8*)&S_bf[(size_t)h * SR4 + g * 16];
    w1v.v = *(const short8*)&S_bf[(size_t)h * SR4 + g * 16 + 8];
    float sum = 0.f;
#pragma unroll
    for (int p = 0; p < 4; ++p) {
      sum += __uint_as_float(w0v.u[p] << 16) + __uint_as_float(w0v.u[p] & 0xFFFF0000u);
      sum += __uint_as_float(w1v.u[p] << 16) + __uint_as_float(w1v.u[p] & 0xFFFF0000u);
    }
    out[(size_t)(b0 + g) * 256 + h] = sum;
  }

  // ===== phase 2b: wave = (g, qh). U -> Ug[group][c][gg][k] =====
  {
    const int g  = wv & 3;
    const int qh = wv >> 2;
    const int gg = ghalf * 4 + g;
    unsigned short* ugbase = Ug + (((size_t)group * NCH) << 8) + gg * 32;
    short8 af[3];
#pragma unroll
    for (int ft = 0; ft < 3; ++ft) {
      union { short8 v; unsigned short e[8]; } pk;
      int f = ft * 16 + col;
      if (quad < 2 && f < F0) {
        const float* xp = &xs[g][f][quad * 8];
#pragma unroll
        for (int j = 0; j < 8; ++j) pk.e[j] = bf16rne(xp[j]);
      } else {
#pragma unroll
        for (int j = 0; j < 8; ++j) pk.e[j] = 0;
      }
      af[ft] = pk.v;
    }
#pragma unroll
    for (int qi = 0; qi < 4; ++qi) {
      const int qt = qh * 4 + qi;
      short8 bq;
      if (quad < 2) {
        bq = *(const short8*)&S_bf[(size_t)(qt * 16 + col) * SR4 + g * 16 + quad * 8];
      } else {
        bq = short8{0, 0, 0, 0, 0, 0, 0, 0};
      }
      const int k = (qt & 1) * 16 + col;
      const int csub = qt >> 1;
#pragma unroll
      for (int ft = 0; ft < 3; ++ft) {
        floatx4 c2 = mfma16(af[ft], bq, zf4);
#pragma unroll
        for (int r = 0; r < 4; ++r) {
          int f = ft * 16 + quad * 4 + r;
          if (f < F0) {
            int c = f * 4 + csub;
            ugbase[((size_t)c << 8) + k] = bf16rne(c2[r]);
          }
        }
      }
    }
  }
}

// ---------- phase B: partial out2 GEMM (group x k-half) ----------
__global__ __launch_bounds__(512, 4) void cin_phaseB(const short8* __restrict__ wA2,
                                                     const unsigned short* __restrict__ Ug,
                                                     float* __restrict__ P) {
  __shared__ __align__(16) unsigned short Ub[78 * 256];   // 39.9 KB

  const int tid   = threadIdx.x;
  const int lane  = tid & 63;
  const int t     = tid >> 6;    // 8 waves = m-tile
  const int col   = lane & 15;
  const int quad  = lane >> 4;
  const int group = blockIdx.x >> 1;
  const int kh    = blockIdx.x & 1;
  const int c0    = kh * 78;
  const floatx4 zf4 = {0.f, 0.f, 0.f, 0.f};
  const short8 zero8 = {0, 0, 0, 0, 0, 0, 0, 0};

  // ---- stage Ug half-slab (coalesced uint4): 78*256 shorts = 2496 uint4 ----
  {
    const uint4* src = (const uint4*)(Ug + (((size_t)group * NCH + c0) << 8));
    uint4* dst = (uint4*)Ub;
    for (int i = tid; i < 78 * 256 / 8; i += 512) dst[i] = src[i];
  }
  __syncthreads();

  floatx4 acc[4];
#pragma unroll
  for (int i = 0; i < 4; ++i) acc[i] = zf4;

  short8 aW[4];
#pragma unroll
  for (int i = 0; i < 4; ++i)
    aW[i] = wA2[(size_t)((c0 + i) * 8 + t) * 64 + lane];

  for (int jj = 0; jj < 19; ++jj) {
    short8 nx[4];
#pragma unroll
    for (int i = 0; i < 4; ++i) {
      int cn = jj * 4 + 4 + i;
      if (cn > 77) cn = 77;
      nx[i] = wA2[(size_t)((c0 + cn) * 8 + t) * 64 + lane];
    }
#pragma unroll
    for (int i = 0; i < 4; ++i) {
      int ci = jj * 4 + i;
      short8 bU = (col < 8)
          ? *(const short8*)&Ub[(size_t)ci * 256 + col * 32 + quad * 8]
          : zero8;
      acc[i] = mfma16(aW[i], bU, acc[i]);
    }
#pragma unroll
    for (int i = 0; i < 4; ++i) aW[i] = nx[i];
  }
  // tail: chunks 76, 77 (aW[0], aW[1] hold them after the clamped prefetch)
#pragma unroll
  for (int i = 0; i < 2; ++i) {
    int ci = 76 + i;
    short8 bU = (col < 8)
        ? *(const short8*)&Ub[(size_t)ci * 256 + col * 32 + quad * 8]
        : zero8;
    acc[i] = mfma16(aW[i], bU, acc[i]);
  }

  if (col < 8) {
    float* pb = P + (size_t)kh * (2048 * 128) + ((size_t)(group * 8 + col)) * 128;
#pragma unroll
    for (int r = 0; r < 4; ++r) {
      float v = (acc[0][r] + acc[1][r]) + (acc[2][r] + acc[3][r]);
      pb[t * 16 + quad * 4 + r] = v;
    }
  }
}

// ---------- reduce: out2 = P0 + P1 ----------
__global__ __launch_bounds__(256) void cin_reduce(const float* __restrict__ P,
                                                  float* __restrict__ out) {
  int idx = blockIdx.x * 256 + threadIdx.x;   // 65536 float4 slots
  const float4 a = ((const float4*)P)[idx];
  const float4 b = ((const float4*)(P + (size_t)2048 * 128))[idx];
  int bb = idx >> 5;
  int h4 = (idx & 31) * 4;
  float4 s = make_float4(a.x + b.x, a.y + b.y, a.z + b.z, a.w + b.w);
  *(float4*)&out[(size_t)bb * 256 + 128 + h4] = s;
}

// ---------- R8 fused fallback (verified) ----------
__global__ __launch_bounds__(1024, 4) void cin_fused(const float* __restrict__ x,
                                                     const short8* __restrict__ wA1,
                                                     const short8* __restrict__ wA2,
                                                     float* __restrict__ out) {
  __shared__ __align__(16) char smem[19968 + 128 * SROW * 2 + F0 * UFS * 2];
  float (*xs)[F0][D_]   = (float (*)[F0][D_])smem;
  float* S32            = (float*)smem;
  unsigned short* S_bf  = (unsigned short*)(smem + 19968);
  unsigned short* xTb   = (unsigned short*)(smem + 19968 + 128 * SROW * 2);
  unsigned short* Ub2   = xTb;

  const int tid  = threadIdx.x;
  const int lane = tid & 63;
  const int wv   = tid >> 6;
  const int col  = lane & 15;
  const int quad = lane >> 4;
  const int b0   = blockIdx.x * G8;
  const floatx4 zf4 = {0.f, 0.f, 0.f, 0.f};

  {
    const float4* xg = (const float4*)(x + (size_t)b0 * (F0 * D_));
    float4* xl = (float4*)smem;
    for (int i = tid; i < G8 * F0 * D_ / 4; i += 1024) xl[i] = xg[i];
  }
  __syncthreads();
  if (tid < G8 * 8 * D_) {
    int i = tid;
    int d = i & 15, q8 = (i >> 4) & 7, g = i >> 7;
    union { short8 v; unsigned short e[8]; } pk;
#pragma unroll
    for (int j = 0; j < 8; ++j) {
      int q = q8 * 8 + j;
      pk.e[j] = (q < F0) ? bf16rne(xs[g][q][d]) : (unsigned short)0;
    }
    *(short8*)&xTb[(size_t)i * 8] = pk.v;
  }
  __syncthreads();
  {
    const int t  = wv & 7;
    const int g0 = (wv >> 3) * 4;
    short8 bx[2][4];
#pragma unroll
    for (int s = 0; s < 2; ++s)
#pragma unroll
      for (int gi = 0; gi < 4; ++gi)
        bx[s][gi] = *(const short8*)&xTb[(size_t)((((g0 + gi) * 8 + s * 4 + quad) * 16) + col) * 8];
    floatx4 acc2[4];
#pragma unroll
    for (int gi = 0; gi < 4; ++gi) acc2[gi] = zf4;
    short8 a0 = wA1[(size_t)(0 * 8 + t) * 64 + lane];
    short8 a1 = wA1[(size_t)(1 * 8 + t) * 64 + lane];
    for (int f = 0; f < F0; ++f) {
      int fn = (f + 1 < F0) ? f + 1 : f;
      short8 na0 = wA1[(size_t)((fn * 2 + 0) * 8 + t) * 64 + lane];
      short8 na1 = wA1[(size_t)((fn * 2 + 1) * 8 + t) * 64 + lane];
      float sx[4];
#pragma unroll
      for (int gi = 0; gi < 4; ++gi) sx[gi] = xs[g0 + gi][f][col];
#pragma unroll
      for (int gi = 0; gi < 4; ++gi) {
        floatx4 acf = mfma16(a0, bx[0][gi], zf4);
        acf = mfma16(a1, bx[1][gi], acf);
#pragma unroll
        for (int r = 0; r < 4; ++r) acc2[gi][r] += acf[r] * sx[gi];
      }
      a0 = na0; a1 = na1;
    }
#pragma unroll
    for (int gi = 0; gi < 4; ++gi)
#pragma unroll
      for (int r = 0; r < 4; ++r)
        S_bf[(size_t)((t * 16 + quad * 4 + r) * SROW) + (g0 + gi) * 16 + col] =
            bf16rne(acc2[gi][r]);
  }
  __syncthreads();
  {
    int h = tid & 127, g = tid >> 7;
    union { short8 v; unsigned int u[4]; } w0v, w1v;
    w0v.v = *(const short8*)&S_bf[(size_t)h * SROW + g * 16];
    w1v.v = *(const short8*)&S_bf[(size_t)h * SROW + g * 16 + 8];
    float sum = 0.f;
#pragma unroll
    for (int p = 0; p < 4; ++p) {
      sum += __uint_as_float(w0v.u[p] << 16) + __uint_as_float(w0v.u[p] & 0xFFFF0000u);
      sum += __uint_as_float(w1v.u[p] << 16) + __uint_as_float(w1v.u[p] & 0xFFFF0000u);
    }
    out[(size_t)(b0 + g) * 256 + h] = sum;
  }
  {
    const int g  = wv & 7;
    const int qh = wv >> 3;
    short8 af[3];
#pragma unroll
    for (int ft = 0; ft < 3; ++ft) {
      union { short8 v; unsigned short e[8]; } pk;
      int f = ft * 16 + col;
      if (quad < 2 && f < F0) {
        const float* xp = &xs[g][f][quad * 8];
#pragma unroll
        for (int j = 0; j < 8; ++j) pk.e[j] = bf16rne(xp[j]);
      } else {
#pragma unroll
        for (int j = 0; j < 8; ++j) pk.e[j] = 0;
      }
      af[ft] = pk.v;
    }
#pragma unroll
    for (int qi = 0; qi < 4; ++qi) {
      const int qt = qh * 4 + qi;
      short8 bq;
      if (quad < 2) {
        bq = *(const short8*)&S_bf[(size_t)(qt * 16 + col) * SROW + g * 16 + quad * 8];
      } else {
        bq = short8{0, 0, 0, 0, 0, 0, 0, 0};
      }
#pragma unroll
      for (int ft = 0; ft < 3; ++ft) {
        floatx4 c2 = mfma16(af[ft], bq, zf4);
        unsigned short* up =
            &Ub2[(size_t)(ft * 16 + quad * 4) * UFS + g * UGS + qt * 16 + col];
        if (ft < 2) {
#pragma unroll
          for (int r = 0; r < 4; ++r) up[r * UFS] = bf16rne(c2[r]);
        } else {
#pragma unroll
          for (int r = 0; r < 4; ++r)
            if (32 + quad * 4 + r < F0) up[r * UFS] = bf16rne(c2[r]);
        }
      }
    }
  }
  __syncthreads();
  {
    const int t   = wv & 7;
    const int kh  = wv >> 3;
    const int cb0 = kh ? 20 : 0;
    const int cbN = kh ? F0 : 20;
    const short8 zero8 = {0, 0, 0, 0, 0, 0, 0, 0};
    floatx4 aco[4];
#pragma unroll
    for (int i = 0; i < 4; ++i) aco[i] = zf4;
    short8 aW[4];
#pragma unroll
    for (int i = 0; i < 4; ++i) aW[i] = wA2[(size_t)((cb0 * 4 + i) * 8 + t) * 64 + lane];
    for (int cb = cb0; cb < cbN; ++cb) {
      int cn = (cb + 1 < cbN) ? cb + 1 : cb;
      short8 nx[4];
#pragma unroll
      for (int i = 0; i < 4; ++i) nx[i] = wA2[(size_t)((cn * 4 + i) * 8 + t) * 64 + lane];
      const unsigned short* ubase = &Ub2[(size_t)cb * UFS + col * UGS + quad * 8];
#pragma unroll
      for (int i = 0; i < 4; ++i) {
        short8 bU = (col < 8) ? *(const short8*)(ubase + i * 32) : zero8;
        aco[i] = mfma16(aW[i], bU, aco[i]);
      }
#pragma unroll
      for (int i = 0; i < 4; ++i) aW[i] = nx[i];
    }
    float v[4];
#pragma unroll
    for (int r = 0; r < 4; ++r)
      v[r] = (aco[0][r] + aco[1][r]) + (aco[2][r] + aco[3][r]);
    if (kh == 0 && col < 8) {
#pragma unroll
      for (int r = 0; r < 4; ++r)
        S32[(size_t)(t * 16 + quad * 4 + r) * 9 + col] = v[r];
    }
    __syncthreads();
    if (kh == 1 && col < 8) {
#pragma unroll
      for (int r = 0; r < 4; ++r) {
        int h = t * 16 + quad * 4 + r;
        out[(size_t)(b0 + col) * 256 + 128 + h] = v[r] + S32[(size_t)h * 9 + col];
      }
    }
  }
}

extern "C" void kernel_launch(void* const* d_in, const int* in_sizes, int n_in,
                              void* d_out, int out_size, void* d_ws, size_t ws_size,
                              hipStream_t stream) {
  const float* x  = (const float*)d_in[0];
  const float* w0 = (const float*)d_in[1];
  const float* w1 = (const float*)d_in[2];
  float* out = (float*)d_out;

  const size_t nfr    = (size_t)(NF1 + NF2) * 64;                 // 119808
  const size_t wbytes = nfr * sizeof(short8);                     // ~1.92 MB
  const size_t ubytes = (size_t)256 * NCH * 256 * 2;              // 20.4 MB Ug
  const size_t pbytes = (size_t)2 * 2048 * 128 * 4;               // 2 MB partials

  if (ws_size >= wbytes + ubytes + pbytes) {
    short8* wA1 = (short8*)d_ws;
    short8* wA2 = wA1 + (size_t)NF1 * 64;
    unsigned short* Ug = (unsigned short*)(wA2 + (size_t)NF2 * 64);
    float* P = (float*)(Ug + (size_t)256 * NCH * 256);
    pack_w_kernel<<<(int)((nfr + 255) / 256), 256, 0, stream>>>(w0, w1, wA1, wA2);
    cin_phaseA<<<512, 512, 0, stream>>>(x, wA1, out, Ug);
    cin_phaseB<<<512, 512, 0, stream>>>(wA2, Ug, P);
    cin_reduce<<<256, 256, 0, stream>>>(P, out);
  } else if (ws_size >= wbytes) {
    short8* wA1 = (short8*)d_ws;
    short8* wA2 = wA1 + (size_t)NF1 * 64;
    pack_w_kernel<<<(int)((nfr + 255) / 256), 256, 0, stream>>>(w0, w1, wA1, wA2);
    cin_fused<<<256, 1024, 0, stream>>>(x, wA1, wA2, out);
  }
}

// Round 10
// 103.386 us; speedup vs baseline: 1.0379x; 1.0379x over previous
//
#include <hip/hip_runtime.h>

// CIN, d-contraction-first, R10: R9 phaseA + properly-shaped phaseB GEMM.
//   pack   : W0/W1 -> MFMA A-frag order (bf16) in ws
//   phaseA : 512 blocks x 512 thr, G=4, 2 blocks/CU. layer1 + out1 + U;
//            U written ROW-MAJOR Ug[b][4992] (R4-verified indexing)
//   phaseB : 256 blocks = 64 N-tiles(32 batches) x 4 k-slices(39 chunks).
//            B-tile staged to LDS (80KB, row stride 1256 shorts -> 16B-aligned,
//            <=2-way banks), full-width MFMA, 624 MFMA/block, A-frags from L2.
//   reduce : out2 = sum_ks P[ks]
// vs R9: phaseB N=8 half-masked MFMA + 320MB A-traffic -> N=32 full-width +
// 80MB A-traffic; phaseB per-CU cost ~9-15us -> ~4us.

#define F0   39
#define D_   16
#define H_   128
#define P0_  1521
#define P1_  4992
#define NF1  (F0 * 2 * 8)   // 624 layer-1 A-frags
#define NF2  (F0 * 4 * 8)   // 1248 W1 A-frags
#define SR4  72             // phaseA S_bf row stride (shorts)
#define BROW 1256           // phaseB LDS B row stride (shorts; 2512B, 16B-aligned)

typedef __attribute__((ext_vector_type(8))) short   short8;
typedef __attribute__((ext_vector_type(8))) __bf16  bf16x8;
typedef __attribute__((ext_vector_type(4))) float   floatx4;

__device__ __forceinline__ unsigned short bf16rne(float f) {
  unsigned int u = __float_as_uint(f);
  u += 0x7FFFu + ((u >> 16) & 1u);
  return (unsigned short)(u >> 16);
}

__device__ __forceinline__ floatx4 mfma16(short8 a, short8 b, floatx4 c) {
  return __builtin_amdgcn_mfma_f32_16x16x32_bf16(
      __builtin_bit_cast(bf16x8, a), __builtin_bit_cast(bf16x8, b), c, 0, 0, 0);
}

// ---------- pack W into MFMA A-frag order (verified R3-R9) ----------
__global__ __launch_bounds__(256) void pack_w_kernel(const float* __restrict__ w0,
                                                     const float* __restrict__ w1,
                                                     short8* __restrict__ wA1,
                                                     short8* __restrict__ wA2) {
  int id = blockIdx.x * 256 + threadIdx.x;
  union { short8 v; unsigned short e[8]; } pk;
  if (id < NF1 * 64) {
    int lane = id & 63, frag = id >> 6;
    int t = frag & 7, s = (frag >> 3) & 1, f = frag >> 4;
    int m = t * 16 + (lane & 15);
    int qb = s * 32 + (lane >> 4) * 8;
#pragma unroll
    for (int j = 0; j < 8; ++j) {
      int q = qb + j;
      float v = (q < F0) ? w0[(size_t)m * P0_ + f * F0 + q] : 0.f;
      pk.e[j] = bf16rne(v);
    }
    wA1[frag * 64 + lane] = pk.v;
  } else if (id < (NF1 + NF2) * 64) {
    int u = id - NF1 * 64;
    int lane = u & 63, frag = u >> 6;
    int t = frag & 7, s = (frag >> 3) & 3, f = frag >> 5;
    int m = t * 16 + (lane & 15);
    int pb = f * 128 + s * 32 + (lane >> 4) * 8;
#pragma unroll
    for (int j = 0; j < 8; ++j) pk.e[j] = bf16rne(w1[(size_t)m * P1_ + pb + j]);
    wA2[frag * 64 + lane] = pk.v;
  }
}

// ---------- phase A: layer1 + out1 + U (row-major) ----------
__global__ __launch_bounds__(512, 4) void cin_phaseA(const float* __restrict__ x,
                                                     const short8* __restrict__ wA1,
                                                     float* __restrict__ out,
                                                     unsigned short* __restrict__ Ug) {
  __shared__ __align__(16) float xs[4][F0][D_];                 // 9984 B
  __shared__ __align__(16) unsigned short xTb[4 * 8 * D_ * 8];  // 8 KB
  __shared__ __align__(16) unsigned short S_bf[128 * SR4];      // 18.4 KB

  const int tid  = threadIdx.x;
  const int lane = tid & 63;
  const int wv   = tid >> 6;      // 8 waves
  const int col  = lane & 15;
  const int quad = lane >> 4;
  const int b0   = blockIdx.x * 4;
  const floatx4 zf4 = {0.f, 0.f, 0.f, 0.f};

  // ---- stage x (coalesced float4) ----
  {
    const float4* xg = (const float4*)(x + (size_t)b0 * (F0 * D_));
    float4* xl = (float4*)xs;
    for (int i = tid; i < 4 * F0 * D_ / 4; i += 512) xl[i] = xg[i];
  }
  __syncthreads();

  // ---- xTb[g][q8][d][j] = bf16(x[g][q8*8+j][d]), zero-pad q>=39 ----
  {
    int i = tid;  // exactly 512 entries
    int d = i & 15, q8 = (i >> 4) & 7, g = i >> 7;
    union { short8 v; unsigned short e[8]; } pk;
#pragma unroll
    for (int j = 0; j < 8; ++j) {
      int q = q8 * 8 + j;
      pk.e[j] = (q < F0) ? bf16rne(xs[g][q][d]) : (unsigned short)0;
    }
    *(short8*)&xTb[(size_t)i * 8] = pk.v;
  }
  __syncthreads();

  // ===== phase 1: wave = m-tile t; 4 local batches =====
  {
    const int t = wv;
    short8 bx[2][4];
#pragma unroll
    for (int s = 0; s < 2; ++s)
#pragma unroll
      for (int gi = 0; gi < 4; ++gi)
        bx[s][gi] = *(const short8*)&xTb[(size_t)(((gi * 8 + s * 4 + quad) * 16) + col) * 8];

    floatx4 acc2[4];
#pragma unroll
    for (int gi = 0; gi < 4; ++gi) acc2[gi] = zf4;

    short8 a0 = wA1[(size_t)(0 * 8 + t) * 64 + lane];
    short8 a1 = wA1[(size_t)(1 * 8 + t) * 64 + lane];
    for (int f = 0; f < F0; ++f) {
      int fn = (f + 1 < F0) ? f + 1 : f;
      short8 na0 = wA1[(size_t)((fn * 2 + 0) * 8 + t) * 64 + lane];
      short8 na1 = wA1[(size_t)((fn * 2 + 1) * 8 + t) * 64 + lane];
      float sx[4];
#pragma unroll
      for (int gi = 0; gi < 4; ++gi) sx[gi] = xs[gi][f][col];
#pragma unroll
      for (int gi = 0; gi < 4; ++gi) {
        floatx4 acf = mfma16(a0, bx[0][gi], zf4);
        acf = mfma16(a1, bx[1][gi], acf);
#pragma unroll
        for (int r = 0; r < 4; ++r) acc2[gi][r] += acf[r] * sx[gi];
      }
      a0 = na0; a1 = na1;
    }
#pragma unroll
    for (int gi = 0; gi < 4; ++gi)
#pragma unroll
      for (int r = 0; r < 4; ++r)
        S_bf[(size_t)((t * 16 + quad * 4 + r) * SR4) + gi * 16 + col] =
            bf16rne(acc2[gi][r]);
  }
  __syncthreads();

  // ===== phase 2a: out1[b,h] = sum_d h1 =====
  {
    int h = tid & 127, g = tid >> 7;
    union { short8 v; unsigned int u[4]; } w0v, w1v;
    w0v.v = *(const short8*)&S_bf[(size_t)h * SR4 + g * 16];
    w1v.v = *(const short8*)&S_bf[(size_t)h * SR4 + g * 16 + 8];
    float sum = 0.f;
#pragma unroll
    for (int p = 0; p < 4; ++p) {
      sum += __uint_as_float(w0v.u[p] << 16) + __uint_as_float(w0v.u[p] & 0xFFFF0000u);
      sum += __uint_as_float(w1v.u[p] << 16) + __uint_as_float(w1v.u[p] & 0xFFFF0000u);
    }
    out[(size_t)(b0 + g) * 256 + h] = sum;
  }

  // ===== phase 2b: wave = (g, qh). U[b0+g][f*128+q] row-major (R4-verified) =====
  {
    const int g  = wv & 3;
    const int qh = wv >> 2;
    short8 af[3];
#pragma unroll
    for (int ft = 0; ft < 3; ++ft) {
      union { short8 v; unsigned short e[8]; } pk;
      int f = ft * 16 + col;
      if (quad < 2 && f < F0) {
        const float* xp = &xs[g][f][quad * 8];
#pragma unroll
        for (int j = 0; j < 8; ++j) pk.e[j] = bf16rne(xp[j]);
      } else {
#pragma unroll
        for (int j = 0; j < 8; ++j) pk.e[j] = 0;
      }
      af[ft] = pk.v;
    }
#pragma unroll
    for (int qi = 0; qi < 4; ++qi) {
      const int qt = qh * 4 + qi;
      short8 bq;
      if (quad < 2) {
        bq = *(const short8*)&S_bf[(size_t)(qt * 16 + col) * SR4 + g * 16 + quad * 8];
      } else {
        bq = short8{0, 0, 0, 0, 0, 0, 0, 0};
      }
#pragma unroll
      for (int ft = 0; ft < 3; ++ft) {
        floatx4 c2 = mfma16(af[ft], bq, zf4);
#pragma unroll
        for (int r = 0; r < 4; ++r) {
          int f = ft * 16 + quad * 4 + r;
          if (f < F0)
            Ug[(size_t)(b0 + g) * P1_ + f * H_ + qt * 16 + col] = bf16rne(c2[r]);
        }
      }
    }
  }
}

// ---------- phase B: out2 GEMM, N-tile 32 batches x k-slice 39 chunks ----------
__global__ __launch_bounds__(512) void cin_phaseB(const short8* __restrict__ wA2,
                                                  const unsigned short* __restrict__ Ug,
                                                  float* __restrict__ P) {
  __shared__ __align__(16) unsigned short Bs[32 * BROW];   // 80.4 KB

  const int tid  = threadIdx.x;
  const int lane = tid & 63;
  const int t    = tid >> 6;      // 8 waves = m-tile
  const int col  = lane & 15;
  const int quad = lane >> 4;
  const int nb   = blockIdx.x >> 2;   // 64 N-tiles
  const int ks   = blockIdx.x & 3;    // 4 k-slices
  const int b0   = nb * 32;
  const int c0   = ks * 39;
  const floatx4 zf4 = {0.f, 0.f, 0.f, 0.f};

  // ---- stage B-tile: 32 rows x 1248 shorts (2496 B/row) coalesced uint4 ----
  {
    const int b = tid >> 4;       // 0..31
    const int j = tid & 15;       // 16 threads per row
    const uint4* src = (const uint4*)(Ug + (size_t)(b0 + b) * P1_ + c0 * 32);
    uint4* dst = (uint4*)&Bs[(size_t)b * BROW];
#pragma unroll
    for (int jj = 0; jj < 10; ++jj) {
      int idx = jj * 16 + j;
      if (idx < 156) dst[idx] = src[idx];
    }
  }
  __syncthreads();

  floatx4 acc[2];
  acc[0] = zf4; acc[1] = zf4;

  short8 aW = wA2[(size_t)((c0 + 0) * 8 + t) * 64 + lane];
  for (int ci = 0; ci < 39; ++ci) {
    int cn = (ci + 1 < 39) ? ci + 1 : ci;
    short8 nx = wA2[(size_t)((c0 + cn) * 8 + t) * 64 + lane];
#pragma unroll
    for (int nt = 0; nt < 2; ++nt) {
      short8 bU = *(const short8*)&Bs[(size_t)(nt * 16 + col) * BROW + ci * 32 + quad * 8];
      acc[nt] = mfma16(aW, bU, acc[nt]);
    }
    aW = nx;
  }

#pragma unroll
  for (int nt = 0; nt < 2; ++nt) {
    float* pb = P + (size_t)ks * (2048 * 128) + (size_t)(b0 + nt * 16 + col) * 128;
#pragma unroll
    for (int r = 0; r < 4; ++r)
      pb[t * 16 + quad * 4 + r] = acc[nt][r];
  }
}

// ---------- reduce: out2 = sum of 4 partial slices ----------
__global__ __launch_bounds__(256) void cin_reduce(const float* __restrict__ P,
                                                  float* __restrict__ out) {
  int idx = blockIdx.x * 256 + threadIdx.x;   // 65536 float4 slots
  const size_t S = (size_t)2048 * 128;
  float4 a = ((const float4*)P)[idx];
  float4 b = ((const float4*)(P + S))[idx];
  float4 c = ((const float4*)(P + 2 * S))[idx];
  float4 d = ((const float4*)(P + 3 * S))[idx];
  int bb = idx >> 5;
  int h4 = (idx & 31) * 4;
  float4 s = make_float4((a.x + b.x) + (c.x + d.x), (a.y + b.y) + (c.y + d.y),
                         (a.z + b.z) + (c.z + d.z), (a.w + b.w) + (c.w + d.w));
  *(float4*)&out[(size_t)bb * 256 + 128 + h4] = s;
}

extern "C" void kernel_launch(void* const* d_in, const int* in_sizes, int n_in,
                              void* d_out, int out_size, void* d_ws, size_t ws_size,
                              hipStream_t stream) {
  const float* x  = (const float*)d_in[0];
  const float* w0 = (const float*)d_in[1];
  const float* w1 = (const float*)d_in[2];
  float* out = (float*)d_out;

  const size_t nfr = (size_t)(NF1 + NF2) * 64;

  short8* wA1 = (short8*)d_ws;
  short8* wA2 = wA1 + (size_t)NF1 * 64;
  unsigned short* Ug = (unsigned short*)(wA2 + (size_t)NF2 * 64);
  float* P = (float*)(Ug + (size_t)2048 * P1_);

  pack_w_kernel<<<(int)((nfr + 255) / 256), 256, 0, stream>>>(w0, w1, wA1, wA2);
  cin_phaseA<<<512, 512, 0, stream>>>(x, wA1, out, Ug);
  cin_phaseB<<<256, 512, 0, stream>>>(wA2, Ug, P);
  cin_reduce<<<256, 256, 0, stream>>>(P, out);
}